// Round 1
// baseline (659.920 us; speedup 1.0000x reference)
//
#include <hip/hip_runtime.h>
#include <hip/hip_bf16.h>
#include <math.h>

#define S_LEN 2048
#define DHEAD 128
#define NH    32          // B*H
#define BM    64          // q rows per workgroup
#define KT    64          // kv rows per tile
#define NKT   (S_LEN / KT)
#define SCALE 0.08838834764831845f   // 1/sqrt(128)

typedef __attribute__((ext_vector_type(4))) float f32x4;
typedef __attribute__((ext_vector_type(8))) unsigned short u16x8;
typedef __attribute__((ext_vector_type(4))) unsigned short u16x4;
typedef __attribute__((ext_vector_type(8))) __bf16 bf16x8;

static __device__ __forceinline__ unsigned short f2bf(float x) {
  union { float f; unsigned u; } v; v.f = x;
  unsigned r = v.u + 0x7FFFu + ((v.u >> 16) & 1u);   // RNE
  return (unsigned short)(r >> 16);
}
static __device__ __forceinline__ float bf2f(unsigned short h) {
  union { unsigned u; float f; } v; v.u = ((unsigned)h) << 16;
  return v.f;
}
static __device__ __forceinline__ bf16x8 as_bf(u16x8 x) {
  return __builtin_bit_cast(bf16x8, x);
}

// Stage K-tile [64 kv][128 d] fp32 -> bf16 LDS, row-major, XOR-swizzled.
// Optionally also stage the bf16 residual (lo) tile for split-precision QK^T.
template <bool LO>
static __device__ __forceinline__ void stage_k(const float* __restrict__ src,
                                               unsigned short* khi,
                                               unsigned short* klo, int tid) {
  const float4* s4 = (const float4*)src;
#pragma unroll
  for (int p = 0; p < 8; ++p) {
    int idx4 = p * 256 + tid;           // 2048 float4s
    int kv = idx4 >> 5;                 // 32 float4 per row
    int d4 = idx4 & 31;
    float4 v = s4[idx4];                // fully coalesced (512B per 32 lanes)
    float f[4] = {v.x, v.y, v.z, v.w};
    int off = kv * 128 + ((d4 * 4) ^ ((kv & 7) << 3));  // ushort units
    u16x4 hi, lo;
#pragma unroll
    for (int j = 0; j < 4; ++j) {
      unsigned short h = f2bf(f[j]);
      hi[j] = h;
      if constexpr (LO) lo[j] = f2bf(f[j] - bf2f(h));
    }
    *(u16x4*)&khi[off] = hi;
    if constexpr (LO) *(u16x4*)&klo[off] = lo;
  }
}

// Stage V-tile transposed: vtr[d][kv] (bf16, swizzled). Global reads are 64B
// coalesced (4 lanes per kv row); scalar LDS writes land ~4-way conflicted.
static __device__ __forceinline__ void stage_v(const float* __restrict__ src,
                                               unsigned short* vtr, int tid) {
  const float4* s4 = (const float4*)src;
#pragma unroll
  for (int p = 0; p < 8; ++p) {
    int idx4 = p * 256 + tid;
    int kv = (idx4 >> 2) & 63;
    int d4 = (idx4 & 3) | ((idx4 >> 8) << 2);
    float4 v = s4[kv * 32 + d4];
    float f[4] = {v.x, v.y, v.z, v.w};
#pragma unroll
    for (int j = 0; j < 4; ++j) {
      int d = d4 * 4 + j;
      vtr[d * 64 + (kv ^ ((d & 7) << 3))] = f2bf(f[j]);
    }
  }
}

__global__ __launch_bounds__(256) void attn_kernel(
    const float* __restrict__ Qg, const float* __restrict__ Kg,
    const float* __restrict__ Vg, float* __restrict__ out) {
  __shared__ unsigned short khi[KT * DHEAD];   // 16 KB
  __shared__ unsigned short klo[KT * DHEAD];   // 16 KB
  __shared__ unsigned short vtr[DHEAD * KT];   // 16 KB (V transposed)
  __shared__ float pbuf[4 * 16 * 64];          // 16 KB (per-wave P, fp32)

  const int tid = threadIdx.x;
  const int w  = tid >> 6;
  const int l  = tid & 63;
  const int lr = l & 15;   // lane row (n / col index)
  const int lg = l >> 4;   // lane group

  // XCD-aware decode: all 32 q-blocks of a head on the same XCD (dispatch%8).
  const int d_  = blockIdx.x;          // 0..1023
  const int xcd = d_ & 7;
  const int slot = d_ >> 3;            // 0..127
  const int bh = xcd + 8 * (slot >> 5);
  const int qb = slot & 31;

  const size_t head_off = (size_t)bh * S_LEN * DHEAD;
  const float* Qh = Qg + head_off;
  const float* Kh = Kg + head_off;
  const float* Vh = Vg + head_off;
  float* Ov = out + head_off;
  float* Pa = out + (size_t)NH * S_LEN * DHEAD + (size_t)bh * S_LEN * S_LEN;

  // ---- Q fragments (B-operand of S^T = K·Q^T), pre-scaled, hi/lo split ----
  const int qrow = qb * BM + w * 16 + lr;
  const float* qptr = Qh + (size_t)qrow * DHEAD;
  u16x8 qh[4], qlo[4];
#pragma unroll
  for (int kc = 0; kc < 4; ++kc) {
    const float4* qp4 = (const float4*)(qptr + kc * 32 + lg * 8);
    float4 a = qp4[0], b = qp4[1];
    float xs[8] = {a.x, a.y, a.z, a.w, b.x, b.y, b.z, b.w};
#pragma unroll
    for (int i = 0; i < 8; ++i) {
      float x = xs[i] * SCALE;
      unsigned short h = f2bf(x);
      qh[kc][i] = h;
      qlo[kc][i] = f2bf(x - bf2f(h));
    }
  }

  const f32x4 zero4 = {0.f, 0.f, 0.f, 0.f};
  float m = -INFINITY, lsum = 0.f;

  // ================= phase 1: running row max & sum =================
  for (int kt = 0; kt < NKT; ++kt) {
    __syncthreads();
    stage_k<false>(Kh + (size_t)kt * KT * DHEAD, khi, klo, tid);
    __syncthreads();

    f32x4 sacc[4];
#pragma unroll
    for (int mt = 0; mt < 4; ++mt) sacc[mt] = zero4;
#pragma unroll
    for (int mt = 0; mt < 4; ++mt) {
      const int row = mt * 16 + lr;
      const int rbase = row * 128;
      const int sw = (row & 7) << 3;
#pragma unroll
      for (int kc = 0; kc < 4; ++kc) {
        u16x8 kf = *(const u16x8*)&khi[rbase + ((kc * 32 + lg * 8) ^ sw)];
        sacc[mt] = __builtin_amdgcn_mfma_f32_16x16x32_bf16(
            as_bf(kf), as_bf(qh[kc]), sacc[mt], 0, 0, 0);
      }
    }
    float tmax = sacc[0][0];
#pragma unroll
    for (int mt = 0; mt < 4; ++mt)
#pragma unroll
      for (int r = 0; r < 4; ++r) tmax = fmaxf(tmax, sacc[mt][r]);
    tmax = fmaxf(tmax, __shfl_xor(tmax, 16));
    tmax = fmaxf(tmax, __shfl_xor(tmax, 32));
    float mnew = fmaxf(m, tmax);
    float esum = 0.f;
#pragma unroll
    for (int mt = 0; mt < 4; ++mt)
#pragma unroll
      for (int r = 0; r < 4; ++r) esum += __expf(sacc[mt][r] - mnew);
    esum += __shfl_xor(esum, 16);
    esum += __shfl_xor(esum, 32);
    lsum = lsum * __expf(m - mnew) + esum;
    m = mnew;
  }
  const float invl = 1.0f / lsum;

  // ================= phase 2: recompute (split), write P, PV =================
  f32x4 oacc[8];
#pragma unroll
  for (int dt = 0; dt < 8; ++dt) oacc[dt] = zero4;

  float* pw = pbuf + w * (16 * 64);

  for (int kt = 0; kt < NKT; ++kt) {
    __syncthreads();
    stage_k<true>(Kh + (size_t)kt * KT * DHEAD, khi, klo, tid);
    stage_v(Vh + (size_t)kt * KT * DHEAD, vtr, tid);
    __syncthreads();

    f32x4 sacc[4];
#pragma unroll
    for (int mt = 0; mt < 4; ++mt) sacc[mt] = zero4;
#pragma unroll
    for (int mt = 0; mt < 4; ++mt) {
      const int row = mt * 16 + lr;
      const int rbase = row * 128;
      const int sw = (row & 7) << 3;
#pragma unroll
      for (int kc = 0; kc < 4; ++kc) {
        const int doff = (kc * 32 + lg * 8) ^ sw;
        u16x8 kfh = *(const u16x8*)&khi[rbase + doff];
        u16x8 kfl = *(const u16x8*)&klo[rbase + doff];
        sacc[mt] = __builtin_amdgcn_mfma_f32_16x16x32_bf16(
            as_bf(kfh), as_bf(qh[kc]), sacc[mt], 0, 0, 0);
        sacc[mt] = __builtin_amdgcn_mfma_f32_16x16x32_bf16(
            as_bf(kfh), as_bf(qlo[kc]), sacc[mt], 0, 0, 0);
        sacc[mt] = __builtin_amdgcn_mfma_f32_16x16x32_bf16(
            as_bf(kfl), as_bf(qh[kc]), sacc[mt], 0, 0, 0);
      }
    }

    // p = exp(s - m) * invl; transpose S^T-layout -> pw[q][kv] via f32x4 writes
#pragma unroll
    for (int mt = 0; mt < 4; ++mt) {
      f32x4 pv;
#pragma unroll
      for (int r = 0; r < 4; ++r) pv[r] = __expf(sacc[mt][r] - m) * invl;
      const int kv0 = mt * 16 + lg * 4;
      *(f32x4*)&pw[lr * 64 + (kv0 ^ ((lr & 7) << 2))] = pv;
    }

    // coalesced p_attn writes: 4 rows/lane, 256B contiguous per 16 lanes
    const size_t prow_base = (size_t)(qb * BM + w * 16);
#pragma unroll
    for (int j = 0; j < 4; ++j) {
      const int qloc = j * 4 + lg;
      f32x4 v = *(const f32x4*)&pw[qloc * 64 + ((lr * 4) ^ ((qloc & 7) << 2))];
      *(f32x4*)&Pa[(prow_base + qloc) * (size_t)S_LEN + kt * KT + lr * 4] = v;
    }

    // P fragments (A-operand of O = P·V)
    u16x8 pf[2];
#pragma unroll
    for (int kvc = 0; kvc < 2; ++kvc) {
      const int kv0 = kvc * 32 + lg * 8;
      f32x4 x = *(const f32x4*)&pw[lr * 64 + (kv0 ^ ((lr & 7) << 2))];
      f32x4 y = *(const f32x4*)&pw[lr * 64 + ((kv0 + 4) ^ ((lr & 7) << 2))];
#pragma unroll
      for (int i = 0; i < 4; ++i) {
        pf[kvc][i] = f2bf(x[i]);
        pf[kvc][i + 4] = f2bf(y[i]);
      }
    }

    // PV: oacc[dt] covers O[16 q][16 d] per dt
#pragma unroll
    for (int dt = 0; dt < 8; ++dt) {
      const int row = dt * 16 + lr;
      const int rbase = row * 64;
      const int sw = (row & 7) << 3;
#pragma unroll
      for (int kvc = 0; kvc < 2; ++kvc) {
        u16x8 vf = *(const u16x8*)&vtr[rbase + ((kvc * 32 + lg * 8) ^ sw)];
        oacc[dt] = __builtin_amdgcn_mfma_f32_16x16x32_bf16(
            as_bf(pf[kvc]), as_bf(vf), oacc[dt], 0, 0, 0);
      }
    }
  }

  // ---- epilogue: p_val ----
#pragma unroll
  for (int dt = 0; dt < 8; ++dt) {
#pragma unroll
    for (int r = 0; r < 4; ++r) {
      const int qloc = w * 16 + lg * 4 + r;
      Ov[(size_t)(qb * BM + qloc) * DHEAD + dt * 16 + lr] = oacc[dt][r];
    }
  }
}

extern "C" void kernel_launch(void* const* d_in, const int* in_sizes, int n_in,
                              void* d_out, int out_size, void* d_ws,
                              size_t ws_size, hipStream_t stream) {
  const float* Q = (const float*)d_in[0];
  const float* K = (const float*)d_in[1];
  const float* V = (const float*)d_in[2];
  float* out = (float*)d_out;
  (void)in_sizes; (void)n_in; (void)out_size; (void)d_ws; (void)ws_size;
  dim3 grid(NH * (S_LEN / BM));  // 1024, flat for XCD-aware decode
  attn_kernel<<<grid, 256, 0, stream>>>(Q, K, V, out);
}